// Round 1
// baseline (295.355 us; speedup 1.0000x reference)
//
#include <hip/hip_runtime.h>
#include <stdint.h>

#define B 4096
#define D 2048
#define NLAB 128

typedef unsigned long long ull;
typedef __bf16 bf16x8 __attribute__((ext_vector_type(8)));
typedef float f32x4 __attribute__((ext_vector_type(4)));

// ---------------- async global->LDS (16B per lane, wave-uniform LDS base) ----
__device__ __forceinline__ void async_copy16(const unsigned short* g, unsigned short* l) {
  __builtin_amdgcn_global_load_lds(
      (const __attribute__((address_space(1))) unsigned int*)g,
      (__attribute__((address_space(3))) unsigned int*)l,
      16, 0, 0);
}

// ---------------- init ------------------------------------------------------
__global__ void k_init(ull* bp, ull* bn, int* hist, float* total, int* cnt) {
  int i = blockIdx.x * blockDim.x + threadIdx.x;
  if (i < B) {
    bp[i] = 0x00000000FFFFFFFFull;  // dist=0.0, idx-code ~0 -> decodes to idx 0
    bn[i] = ~0ull;                  // +inf sentinel
  }
  if (i < NLAB) hist[i] = 0;
  if (i == 0) { *total = 0.0f; *cnt = 0; }
}

// ---------------- fp32 -> bf16 (RNE) + row squared norms --------------------
__device__ __forceinline__ unsigned f2bf_pack(float lo, float hi) {
  unsigned a = __float_as_uint(lo), b = __float_as_uint(hi);
  a = (a + 0x7FFFu + ((a >> 16) & 1u)) >> 16;
  b = (b + 0x7FFFu + ((b >> 16) & 1u)) >> 16;
  return a | (b << 16);
}

__global__ void k_convert_sq(const float* __restrict__ emb,
                             unsigned short* __restrict__ embh,
                             float* __restrict__ sq) {
  const int row = blockIdx.x, t = threadIdx.x;
  const float4* src = (const float4*)(emb + (size_t)row * D);
  float4 v0 = src[2 * t], v1 = src[2 * t + 1];
  float s = v0.x * v0.x + v0.y * v0.y + v0.z * v0.z + v0.w * v0.w
          + v1.x * v1.x + v1.y * v1.y + v1.z * v1.z + v1.w * v1.w;
  uint4 o;
  o.x = f2bf_pack(v0.x, v0.y);
  o.y = f2bf_pack(v0.z, v0.w);
  o.z = f2bf_pack(v1.x, v1.y);
  o.w = f2bf_pack(v1.z, v1.w);
  ((uint4*)(embh + (size_t)row * D))[t] = o;

  for (int off = 32; off; off >>= 1) s += __shfl_down(s, off, 64);
  __shared__ float ps[4];
  int lane = t & 63, wave = t >> 6;
  if (lane == 0) ps[wave] = s;
  __syncthreads();
  if (t == 0) sq[row] = ps[0] + ps[1] + ps[2] + ps[3];
}

// ---------------- label histogram -------------------------------------------
__global__ void k_hist(const int* __restrict__ labels, int* __restrict__ hist) {
  int i = blockIdx.x * blockDim.x + threadIdx.x;
  if (i < B) atomicAdd(&hist[labels[i]], 1);
}

// ---------------- fused GEMM (bf16 MFMA) + hard pos/neg selection -----------
// 128x128 tile, BK=32, 256 threads = 4 waves (2x2), each wave 64x64 via 4x4
// mfma_f32_16x16x32_bf16. LDS tiles stored with XOR chunk swizzle:
// row r (64B = 4 chunks of 16B), slot s holds global chunk g = s ^ ((r>>1)&3).
__launch_bounds__(256)
__global__ void k_gemm_select(const unsigned short* __restrict__ embh,
                              const float* __restrict__ sq,
                              const int* __restrict__ labels,
                              ull* __restrict__ best_pos,
                              ull* __restrict__ best_neg) {
  __shared__ unsigned short ldsA[128 * 32];
  __shared__ unsigned short ldsB[128 * 32];

  const int tid  = threadIdx.x;
  const int lane = tid & 63;
  const int wave = tid >> 6;
  const int wm = wave >> 1, wn = wave & 1;
  const int q = lane >> 4, m15 = lane & 15;
  const int ibase = blockIdx.y * 128, jbase = blockIdx.x * 128;

  // fragment read offsets (elements): want chunk q of row m -> slot q^((m>>1)&3)
  const int slotRead = (q ^ ((m15 >> 1) & 3)) * 8;
  int aoff[4], boff[4];
#pragma unroll
  for (int x = 0; x < 4; ++x) {
    aoff[x] = (wm * 64 + x * 16 + m15) * 32 + slotRead;
    boff[x] = (wn * 64 + x * 16 + m15) * 32 + slotRead;
  }

  const int srow = lane >> 2;   // row within 16-row staging group
  const int slot = lane & 3;    // 16B slot within row

  f32x4 acc[4][4];
  const f32x4 z = {0.f, 0.f, 0.f, 0.f};
#pragma unroll
  for (int a = 0; a < 4; ++a)
#pragma unroll
    for (int b = 0; b < 4; ++b) acc[a][b] = z;

  for (int kb = 0; kb < D; kb += 32) {
    __syncthreads();
#pragma unroll
    for (int p = 0; p < 2; ++p) {
      int r0  = p * 64 + wave * 16;          // wave-uniform
      int row = r0 + srow;
      int g   = (slot ^ ((row >> 1) & 3)) * 8;
      const unsigned short* ga = embh + (size_t)(ibase + row) * D + kb + g;
      const unsigned short* gb = embh + (size_t)(jbase + row) * D + kb + g;
      async_copy16(ga, &ldsA[r0 * 32]);
      async_copy16(gb, &ldsB[r0 * 32]);
    }
    __syncthreads();

    bf16x8 af[4], bfr[4];
#pragma unroll
    for (int x = 0; x < 4; ++x) af[x] = *(const bf16x8*)&ldsA[aoff[x]];
#pragma unroll
    for (int x = 0; x < 4; ++x) bfr[x] = *(const bf16x8*)&ldsB[boff[x]];
#pragma unroll
    for (int mi = 0; mi < 4; ++mi)
#pragma unroll
      for (int ni = 0; ni < 4; ++ni)
        acc[mi][ni] = __builtin_amdgcn_mfma_f32_16x16x32_bf16(
            af[mi], bfr[ni], acc[mi][ni], 0, 0, 0);
  }

  // ---- epilogue: dist + packed argmax/argmin per row ----
  float sqj[4];
  int labj[4];
#pragma unroll
  for (int ni = 0; ni < 4; ++ni) {
    int jj = jbase + wn * 64 + ni * 16 + m15;
    sqj[ni] = sq[jj];
    labj[ni] = labels[jj];
  }

#pragma unroll
  for (int mi = 0; mi < 4; ++mi) {
#pragma unroll
    for (int r = 0; r < 4; ++r) {
      const int i = ibase + wm * 64 + mi * 16 + q * 4 + r;  // C/D: row=(lane>>4)*4+r
      const float si = sq[i];
      const int li = labels[i];
      ull bp = 0x00000000FFFFFFFFull;
      ull bn = ~0ull;
#pragma unroll
      for (int ni = 0; ni < 4; ++ni) {
        int jj = jbase + wn * 64 + ni * 16 + m15;           // C/D: col=lane&15
        float dot = acc[mi][ni][r];
        float d2 = si + sqj[ni] - 2.0f * dot;
        float dist = sqrtf(fmaxf(d2, 0.0f));
        ull pv = ((ull)__float_as_uint(dist)) << 32;
        bool same = (labj[ni] == li);
        if (same && (jj != i)) {
          ull c = pv | (unsigned)(~jj);   // max -> smallest idx wins ties
          bp = bp > c ? bp : c;
        }
        if (!same) {
          ull c = pv | (unsigned)jj;      // min -> smallest idx wins ties
          bn = bn < c ? bn : c;
        }
      }
#pragma unroll
      for (int off = 1; off <= 8; off <<= 1) {
        ull op = __shfl_xor(bp, off, 64);
        ull on = __shfl_xor(bn, off, 64);
        bp = bp > op ? bp : op;
        bn = bn < on ? bn : on;
      }
      if (m15 == 0) {
        atomicMax(&best_pos[i], bp);
        atomicMin(&best_neg[i], bn);
      }
    }
  }
}

// ---------------- exact per-anchor loss (fp32, with eps) --------------------
__global__ void k_anchor(const float* __restrict__ emb, const int* __restrict__ labels,
                         const ull* __restrict__ best_pos, const ull* __restrict__ best_neg,
                         const int* __restrict__ hist,
                         float* __restrict__ total, int* __restrict__ cnt) {
  const int i = blockIdx.x, t = threadIdx.x;
  unsigned pRaw = ~(unsigned)best_pos[i];
  unsigned nRaw = (unsigned)best_neg[i];
  int p = pRaw < (unsigned)B ? (int)pRaw : 0;
  int n = nRaw < (unsigned)B ? (int)nRaw : 0;

  const float4* ei = (const float4*)(emb + (size_t)i * D);
  const float4* ep = (const float4*)(emb + (size_t)p * D);
  const float4* en = (const float4*)(emb + (size_t)n * D);
  float sp = 0.f, sn = 0.f;
#pragma unroll
  for (int c = 0; c < 2; ++c) {
    float4 a = ei[2 * t + c], vp = ep[2 * t + c], vn = en[2 * t + c];
    float d;
    d = a.x - vp.x + 1e-6f; sp += d * d;
    d = a.y - vp.y + 1e-6f; sp += d * d;
    d = a.z - vp.z + 1e-6f; sp += d * d;
    d = a.w - vp.w + 1e-6f; sp += d * d;
    d = a.x - vn.x + 1e-6f; sn += d * d;
    d = a.y - vn.y + 1e-6f; sn += d * d;
    d = a.z - vn.z + 1e-6f; sn += d * d;
    d = a.w - vn.w + 1e-6f; sn += d * d;
  }
  for (int off = 32; off; off >>= 1) {
    sp += __shfl_down(sp, off, 64);
    sn += __shfl_down(sn, off, 64);
  }
  __shared__ float psp[4], psn[4];
  int lane = t & 63, wave = t >> 6;
  if (lane == 0) { psp[wave] = sp; psn[wave] = sn; }
  __syncthreads();
  if (t == 0) {
    float dp = sqrtf(psp[0] + psp[1] + psp[2] + psp[3]);
    float dn = sqrtf(psn[0] + psn[1] + psn[2] + psn[3]);
    float per = fmaxf(dp - dn + 0.3f, 0.f);
    int c = hist[labels[i]];
    if (c >= 2 && c < B) {  // has positive && has negative
      atomicAdd(total, per);
      atomicAdd(cnt, 1);
    }
  }
}

// ---------------- finalize ---------------------------------------------------
__global__ void k_finalize(const float* total, const int* cnt, float* out) {
  int c = *cnt;
  out[0] = c > 0 ? (*total) / (float)c : 0.0f;
}

// ---------------- launch -----------------------------------------------------
extern "C" void kernel_launch(void* const* d_in, const int* in_sizes, int n_in,
                              void* d_out, int out_size, void* d_ws, size_t ws_size,
                              hipStream_t stream) {
  const float* emb = (const float*)d_in[0];
  const int* labels = (const int*)d_in[1];
  float* out = (float*)d_out;
  char* ws = (char*)d_ws;

  const size_t off_embh = 0;
  const size_t off_sq   = off_embh + (size_t)B * D * 2;   // 16 MiB
  const size_t off_bp   = off_sq + (size_t)B * 4;
  const size_t off_bn   = off_bp + (size_t)B * 8;
  const size_t off_hist = off_bn + (size_t)B * 8;
  const size_t off_tot  = off_hist + NLAB * 4;
  const size_t off_cnt  = off_tot + 4;

  unsigned short* embh = (unsigned short*)(ws + off_embh);
  float* sq   = (float*)(ws + off_sq);
  ull* bp     = (ull*)(ws + off_bp);
  ull* bn     = (ull*)(ws + off_bn);
  int* hist   = (int*)(ws + off_hist);
  float* tot  = (float*)(ws + off_tot);
  int* cnt    = (int*)(ws + off_cnt);

  hipLaunchKernelGGL(k_init, dim3(16), dim3(256), 0, stream, bp, bn, hist, tot, cnt);
  hipLaunchKernelGGL(k_convert_sq, dim3(B), dim3(256), 0, stream, emb, embh, sq);
  hipLaunchKernelGGL(k_hist, dim3(16), dim3(256), 0, stream, labels, hist);
  hipLaunchKernelGGL(k_gemm_select, dim3(32, 32), dim3(256), 0, stream,
                     embh, sq, labels, bp, bn);
  hipLaunchKernelGGL(k_anchor, dim3(B), dim3(256), 0, stream,
                     emb, labels, bp, bn, hist, tot, cnt);
  hipLaunchKernelGGL(k_finalize, dim3(1), dim3(1), 0, stream, tot, cnt, out);
}

// Round 2
// 195.541 us; speedup vs baseline: 1.5105x; 1.5105x over previous
//
#include <hip/hip_runtime.h>
#include <stdint.h>

#define B 4096
#define D 2048
#define NLAB 128

typedef unsigned long long ull;
typedef __bf16 bf16x8 __attribute__((ext_vector_type(8)));
typedef float f32x4 __attribute__((ext_vector_type(4)));

#define SENT_P 0x00000000FFFFFFFFull  // dist=0.0, ~idx -> decodes to idx 0
#define SENT_N (~0ull)                // +inf

// ---------------- async global->LDS (16B per lane, wave-uniform LDS base) ----
__device__ __forceinline__ void async_copy16(const unsigned short* g, unsigned short* l) {
  __builtin_amdgcn_global_load_lds(
      (const __attribute__((address_space(1))) unsigned int*)g,
      (__attribute__((address_space(3))) unsigned int*)l,
      16, 0, 0);
}

// ---------------- init ------------------------------------------------------
__global__ void k_init(ull* bp, ull* bn, int* hist, float* total, int* cnt) {
  int i = blockIdx.x * blockDim.x + threadIdx.x;
  if (i < B) {
    bp[i] = SENT_P;
    bn[i] = SENT_N;
  }
  if (i < NLAB) hist[i] = 0;
  if (i == 0) { *total = 0.0f; *cnt = 0; }
}

// ---------------- fp32 -> bf16 (RNE) + row sq-norm + row sum + hist ---------
__device__ __forceinline__ unsigned f2bf_pack(float lo, float hi) {
  unsigned a = __float_as_uint(lo), b = __float_as_uint(hi);
  a = (a + 0x7FFFu + ((a >> 16) & 1u)) >> 16;
  b = (b + 0x7FFFu + ((b >> 16) & 1u)) >> 16;
  return a | (b << 16);
}

__global__ void k_convert_sq(const float* __restrict__ emb,
                             const int* __restrict__ labels,
                             unsigned short* __restrict__ embh,
                             float* __restrict__ sq,
                             float* __restrict__ rs,
                             int* __restrict__ hist) {
  const int row = blockIdx.x, t = threadIdx.x;
  const float4* src = (const float4*)(emb + (size_t)row * D);
  float4 v0 = src[2 * t], v1 = src[2 * t + 1];
  float s = v0.x * v0.x + v0.y * v0.y + v0.z * v0.z + v0.w * v0.w
          + v1.x * v1.x + v1.y * v1.y + v1.z * v1.z + v1.w * v1.w;
  float sm = v0.x + v0.y + v0.z + v0.w + v1.x + v1.y + v1.z + v1.w;
  uint4 o;
  o.x = f2bf_pack(v0.x, v0.y);
  o.y = f2bf_pack(v0.z, v0.w);
  o.z = f2bf_pack(v1.x, v1.y);
  o.w = f2bf_pack(v1.z, v1.w);
  ((uint4*)(embh + (size_t)row * D))[t] = o;

  for (int off = 32; off; off >>= 1) {
    s  += __shfl_down(s, off, 64);
    sm += __shfl_down(sm, off, 64);
  }
  __shared__ float ps[4], pm[4];
  int lane = t & 63, wave = t >> 6;
  if (lane == 0) { ps[wave] = s; pm[wave] = sm; }
  __syncthreads();
  if (t == 0) {
    sq[row] = ps[0] + ps[1] + ps[2] + ps[3];
    rs[row] = pm[0] + pm[1] + pm[2] + pm[3];
    atomicAdd(&hist[labels[row]], 1);
  }
}

// ---------------- fused symmetric GEMM + hard pos/neg selection -------------
// Upper-triangle 128x128 tiles (528 blocks of a 32x32 grid). BK=32, 4 waves
// (2x2), each wave 64x64 via 4x4 mfma_f32_16x16x32_bf16. Off-diagonal tiles
// update both row-i bests and row-j bests (symmetry). XOR chunk swizzle in
// LDS keeps ds_read_b128 conflict-free while satisfying global_load_lds's
// wave-uniform-base constraint.
__launch_bounds__(256)
__global__ void k_gemm_select(const unsigned short* __restrict__ embh,
                              const float* __restrict__ sq,
                              const int* __restrict__ labels,
                              ull* __restrict__ best_pos,
                              ull* __restrict__ best_neg) {
  __shared__ unsigned short ldsA[128 * 32];
  __shared__ unsigned short ldsB[128 * 32];

  // linear bid -> (by, bx) upper triangle (bx >= by)
  int rem = blockIdx.x, by = 0;
  while (rem >= 32 - by) { rem -= 32 - by; ++by; }
  const int bx = by + rem;
  const bool offdiag = (bx != by);

  const int tid  = threadIdx.x;
  const int lane = tid & 63;
  const int wave = tid >> 6;
  const int wm = wave >> 1, wn = wave & 1;
  const int q = lane >> 4, m15 = lane & 15;
  const int ibase = by * 128, jbase = bx * 128;

  const int slotRead = (q ^ ((m15 >> 1) & 3)) * 8;
  int aoff[4], boff[4];
#pragma unroll
  for (int x = 0; x < 4; ++x) {
    aoff[x] = (wm * 64 + x * 16 + m15) * 32 + slotRead;
    boff[x] = (wn * 64 + x * 16 + m15) * 32 + slotRead;
  }

  const int srow = lane >> 2;
  const int slot = lane & 3;

  f32x4 acc[4][4];
  const f32x4 z = {0.f, 0.f, 0.f, 0.f};
#pragma unroll
  for (int a = 0; a < 4; ++a)
#pragma unroll
    for (int b = 0; b < 4; ++b) acc[a][b] = z;

  for (int kb = 0; kb < D; kb += 32) {
    __syncthreads();
#pragma unroll
    for (int p = 0; p < 2; ++p) {
      int r0  = p * 64 + wave * 16;  // wave-uniform
      int row = r0 + srow;
      int g   = (slot ^ ((row >> 1) & 3)) * 8;
      const unsigned short* ga = embh + (size_t)(ibase + row) * D + kb + g;
      const unsigned short* gb = embh + (size_t)(jbase + row) * D + kb + g;
      async_copy16(ga, &ldsA[r0 * 32]);
      async_copy16(gb, &ldsB[r0 * 32]);
    }
    __syncthreads();

    bf16x8 af[4], bfr[4];
#pragma unroll
    for (int x = 0; x < 4; ++x) af[x] = *(const bf16x8*)&ldsA[aoff[x]];
#pragma unroll
    for (int x = 0; x < 4; ++x) bfr[x] = *(const bf16x8*)&ldsB[boff[x]];
#pragma unroll
    for (int mi = 0; mi < 4; ++mi)
#pragma unroll
      for (int ni = 0; ni < 4; ++ni)
        acc[mi][ni] = __builtin_amdgcn_mfma_f32_16x16x32_bf16(
            af[mi], bfr[ni], acc[mi][ni], 0, 0, 0);
  }

  // ---- epilogue ----
  float sqj[4];
  int labj[4];
#pragma unroll
  for (int ni = 0; ni < 4; ++ni) {
    int jj = jbase + wn * 64 + ni * 16 + m15;
    sqj[ni] = sq[jj];
    labj[ni] = labels[jj];
  }

  ull colBp[4], colBn[4];
#pragma unroll
  for (int ni = 0; ni < 4; ++ni) { colBp[ni] = SENT_P; colBn[ni] = SENT_N; }

#pragma unroll
  for (int mi = 0; mi < 4; ++mi) {
#pragma unroll
    for (int r = 0; r < 4; ++r) {
      const int i = ibase + wm * 64 + mi * 16 + q * 4 + r;  // C/D row=(lane>>4)*4+r
      const float si = sq[i];
      const int li = labels[i];
      ull bp = SENT_P;
      ull bn = SENT_N;
#pragma unroll
      for (int ni = 0; ni < 4; ++ni) {
        int jj = jbase + wn * 64 + ni * 16 + m15;            // C/D col=lane&15
        float dot = acc[mi][ni][r];
        float d2 = si + sqj[ni] - 2.0f * dot;
        float dist = sqrtf(fmaxf(d2, 0.0f));
        ull pv = ((ull)__float_as_uint(dist)) << 32;
        bool same = (labj[ni] == li);
        bool notself = (jj != i);
        if (same && notself) {
          ull c = pv | (unsigned)(~jj);  // max -> smallest idx wins ties
          bp = bp > c ? bp : c;
          if (offdiag) {
            ull cc = pv | (unsigned)(~i);
            colBp[ni] = colBp[ni] > cc ? colBp[ni] : cc;
          }
        }
        if (!same) {
          ull c = pv | (unsigned)jj;     // min -> smallest idx wins ties
          bn = bn < c ? bn : c;
          if (offdiag) {
            ull cc = pv | (unsigned)i;
            colBn[ni] = colBn[ni] < cc ? colBn[ni] : cc;
          }
        }
      }
      // row-i reduction across the 16 column lanes (m15 bits)
#pragma unroll
      for (int off = 1; off <= 8; off <<= 1) {
        ull op = __shfl_xor(bp, off, 64);
        ull on = __shfl_xor(bn, off, 64);
        bp = bp > op ? bp : op;
        bn = bn < on ? bn : on;
      }
      if (m15 == 0) {
        atomicMax(&best_pos[i], bp);
        atomicMin(&best_neg[i], bn);
      }
    }
  }

  if (offdiag) {
    // row-j (column) reduction across the 4 q lane-groups
#pragma unroll
    for (int ni = 0; ni < 4; ++ni) {
      ull cp = colBp[ni], cn = colBn[ni];
#pragma unroll
      for (int off = 16; off <= 32; off <<= 1) {
        ull op = __shfl_xor(cp, off, 64);
        ull on = __shfl_xor(cn, off, 64);
        cp = cp > op ? cp : op;
        cn = cn < on ? cn : on;
      }
      if (q == 0) {
        int j = jbase + wn * 64 + ni * 16 + m15;
        atomicMax(&best_pos[j], cp);
        atomicMin(&best_neg[j], cn);
      }
    }
  }
}

// ---------------- loss from packed bests (eps-corrected, no emb re-read) ----
__global__ void k_loss(const int* __restrict__ labels,
                       const ull* __restrict__ best_pos, const ull* __restrict__ best_neg,
                       const float* __restrict__ rs, const int* __restrict__ hist,
                       float* __restrict__ total, int* __restrict__ cnt) {
  const int i = blockIdx.x * blockDim.x + threadIdx.x;
  float per = 0.0f;
  int v = 0;
  int c = hist[labels[i]];
  if (c >= 2 && c < B) {  // has positive && has negative
    ull bp = best_pos[i], bn = best_neg[i];
    unsigned pRaw = ~(unsigned)bp;
    unsigned nRaw = (unsigned)bn;
    int p = pRaw < (unsigned)B ? (int)pRaw : 0;
    int n = nRaw < (unsigned)B ? (int)nRaw : 0;
    float distp = __uint_as_float((unsigned)(bp >> 32));
    float distn = __uint_as_float((unsigned)(bn >> 32));
    float ri = rs[i];
    // ||x + eps*1||^2 = ||x||^2 + 2 eps (sum_i - sum_j) + D eps^2
    const float e = 1e-6f, de2 = (float)D * 1e-12f;
    float dp2 = distp * distp + 2.0f * e * (ri - rs[p]) + de2;
    float dn2 = distn * distn + 2.0f * e * (ri - rs[n]) + de2;
    float dp = sqrtf(fmaxf(dp2, 0.0f));
    float dn = sqrtf(fmaxf(dn2, 0.0f));
    per = fmaxf(dp - dn + 0.3f, 0.0f);
    v = 1;
  }
  // block reduce
  for (int off = 32; off; off >>= 1) {
    per += __shfl_down(per, off, 64);
    v   += __shfl_down(v, off, 64);
  }
  __shared__ float pps[4];
  __shared__ int pvs[4];
  int lane = threadIdx.x & 63, wave = threadIdx.x >> 6;
  if (lane == 0) { pps[wave] = per; pvs[wave] = v; }
  __syncthreads();
  if (threadIdx.x == 0) {
    atomicAdd(total, pps[0] + pps[1] + pps[2] + pps[3]);
    atomicAdd(cnt, pvs[0] + pvs[1] + pvs[2] + pvs[3]);
  }
}

// ---------------- finalize ---------------------------------------------------
__global__ void k_finalize(const float* total, const int* cnt, float* out) {
  int c = *cnt;
  out[0] = c > 0 ? (*total) / (float)c : 0.0f;
}

// ---------------- launch -----------------------------------------------------
extern "C" void kernel_launch(void* const* d_in, const int* in_sizes, int n_in,
                              void* d_out, int out_size, void* d_ws, size_t ws_size,
                              hipStream_t stream) {
  const float* emb = (const float*)d_in[0];
  const int* labels = (const int*)d_in[1];
  float* out = (float*)d_out;
  char* ws = (char*)d_ws;

  const size_t off_embh = 0;
  const size_t off_sq   = off_embh + (size_t)B * D * 2;   // 16 MiB
  const size_t off_rs   = off_sq + (size_t)B * 4;
  const size_t off_bp   = off_rs + (size_t)B * 4;
  const size_t off_bn   = off_bp + (size_t)B * 8;
  const size_t off_hist = off_bn + (size_t)B * 8;
  const size_t off_tot  = off_hist + NLAB * 4;
  const size_t off_cnt  = off_tot + 4;

  unsigned short* embh = (unsigned short*)(ws + off_embh);
  float* sq   = (float*)(ws + off_sq);
  float* rs   = (float*)(ws + off_rs);
  ull* bp     = (ull*)(ws + off_bp);
  ull* bn     = (ull*)(ws + off_bn);
  int* hist   = (int*)(ws + off_hist);
  float* tot  = (float*)(ws + off_tot);
  int* cnt    = (int*)(ws + off_cnt);

  hipLaunchKernelGGL(k_init, dim3(16), dim3(256), 0, stream, bp, bn, hist, tot, cnt);
  hipLaunchKernelGGL(k_convert_sq, dim3(B), dim3(256), 0, stream,
                     emb, labels, embh, sq, rs, hist);
  hipLaunchKernelGGL(k_gemm_select, dim3(528), dim3(256), 0, stream,
                     embh, sq, labels, bp, bn);
  hipLaunchKernelGGL(k_loss, dim3(16), dim3(256), 0, stream,
                     labels, bp, bn, rs, hist, tot, cnt);
  hipLaunchKernelGGL(k_finalize, dim3(1), dim3(1), 0, stream, tot, cnt, out);
}

// Round 3
// 169.965 us; speedup vs baseline: 1.7377x; 1.1505x over previous
//
#include <hip/hip_runtime.h>
#include <stdint.h>

#define B 4096
#define D 2048
#define NLAB 128

typedef unsigned long long ull;
typedef __bf16 bf16x8 __attribute__((ext_vector_type(8)));
typedef float f32x4 __attribute__((ext_vector_type(4)));

#define SENT_P 0x00000000FFFFFFFFull  // dist=0.0, ~idx -> decodes to idx 0
#define SENT_N (~0ull)                // +inf

// ---------------- async global->LDS (16B per lane, wave-uniform LDS base) ----
__device__ __forceinline__ void async_copy16(const unsigned short* g, unsigned short* l) {
  __builtin_amdgcn_global_load_lds(
      (const __attribute__((address_space(1))) unsigned int*)g,
      (__attribute__((address_space(3))) unsigned int*)l,
      16, 0, 0);
}

// ---------------- init ------------------------------------------------------
__global__ void k_init(ull* bp, ull* bn, int* hist, float* total, int* cnt) {
  int i = blockIdx.x * blockDim.x + threadIdx.x;
  if (i < B) {
    bp[i] = SENT_P;
    bn[i] = SENT_N;
  }
  if (i < NLAB) hist[i] = 0;
  if (i == 0) { *total = 0.0f; *cnt = 0; }
}

// ---------------- fp32 -> bf16 (RNE) + row sq-norm + row sum + hist ---------
__device__ __forceinline__ unsigned f2bf_pack(float lo, float hi) {
  unsigned a = __float_as_uint(lo), b = __float_as_uint(hi);
  a = (a + 0x7FFFu + ((a >> 16) & 1u)) >> 16;
  b = (b + 0x7FFFu + ((b >> 16) & 1u)) >> 16;
  return a | (b << 16);
}

__global__ void k_convert_sq(const float* __restrict__ emb,
                             const int* __restrict__ labels,
                             unsigned short* __restrict__ embh,
                             float* __restrict__ sq,
                             float* __restrict__ rs,
                             int* __restrict__ hist) {
  const int row = blockIdx.x, t = threadIdx.x;
  const float4* src = (const float4*)(emb + (size_t)row * D);
  float4 v0 = src[2 * t], v1 = src[2 * t + 1];
  float s = v0.x * v0.x + v0.y * v0.y + v0.z * v0.z + v0.w * v0.w
          + v1.x * v1.x + v1.y * v1.y + v1.z * v1.z + v1.w * v1.w;
  float sm = v0.x + v0.y + v0.z + v0.w + v1.x + v1.y + v1.z + v1.w;
  uint4 o;
  o.x = f2bf_pack(v0.x, v0.y);
  o.y = f2bf_pack(v0.z, v0.w);
  o.z = f2bf_pack(v1.x, v1.y);
  o.w = f2bf_pack(v1.z, v1.w);
  ((uint4*)(embh + (size_t)row * D))[t] = o;

  for (int off = 32; off; off >>= 1) {
    s  += __shfl_down(s, off, 64);
    sm += __shfl_down(sm, off, 64);
  }
  __shared__ float ps[4], pm[4];
  int lane = t & 63, wave = t >> 6;
  if (lane == 0) { ps[wave] = s; pm[wave] = sm; }
  __syncthreads();
  if (t == 0) {
    sq[row] = ps[0] + ps[1] + ps[2] + ps[3];
    rs[row] = pm[0] + pm[1] + pm[2] + pm[3];
    atomicAdd(&hist[labels[row]], 1);
  }
}

// ---------------- fused symmetric GEMM + hard pos/neg selection -------------
// 64x128 tiles covering the strict upper triangle (j > i): 1056 blocks.
// 4 waves (2x2), each wave 32x64 via 2x4 mfma_f32_16x16x32_bf16. Every
// element with j > i updates BOTH anchor i (row side) and anchor j (col
// side); each unordered pair lives in exactly one launched tile, so the
// uniform j>i predicate gives complete coverage incl. diagonal-straddling
// tiles. XOR chunk swizzle keeps ds_read_b128 conflict-free under
// global_load_lds's wave-uniform-base constraint.
__launch_bounds__(256, 4)
__global__ void k_gemm_select(const unsigned short* __restrict__ embh,
                              const float* __restrict__ sq,
                              const int* __restrict__ labels,
                              ull* __restrict__ best_pos,
                              ull* __restrict__ best_neg) {
  __shared__ unsigned short ldsA[64 * 32];
  __shared__ unsigned short ldsB[128 * 32];

  // linear bid -> (by in [0,64), bx in [0,32)) with bx*128+127 > by*64
  int rem = blockIdx.x, p = 0;
  while (rem >= 2 * (32 - p)) { rem -= 2 * (32 - p); ++p; }
  int by = 2 * p;
  int c = 32 - p;
  if (rem >= c) { by += 1; rem -= c; }
  const int bx = p + rem;

  const int tid  = threadIdx.x;
  const int lane = tid & 63;
  const int wave = tid >> 6;
  const int wm = wave >> 1, wn = wave & 1;
  const int q = lane >> 4, m15 = lane & 15;
  const int ibase = by * 64, jbase = bx * 128;

  const int slotRead = (q ^ ((m15 >> 1) & 3)) * 8;
  int aoff[2], boff[4];
#pragma unroll
  for (int x = 0; x < 2; ++x)
    aoff[x] = (wm * 32 + x * 16 + m15) * 32 + slotRead;
#pragma unroll
  for (int x = 0; x < 4; ++x)
    boff[x] = (wn * 64 + x * 16 + m15) * 32 + slotRead;

  const int srow = lane >> 2;  // row within 16-row staging group
  const int slot = lane & 3;   // 16B slot within row

  f32x4 acc[2][4];
  const f32x4 z = {0.f, 0.f, 0.f, 0.f};
#pragma unroll
  for (int a = 0; a < 2; ++a)
#pragma unroll
    for (int b = 0; b < 4; ++b) acc[a][b] = z;

  for (int kb = 0; kb < D; kb += 32) {
    __syncthreads();
    {
      // A: 64 rows -> 4 issues, one per wave
      int r0  = wave * 16;  // wave-uniform
      int row = r0 + srow;
      int g   = (slot ^ ((row >> 1) & 3)) * 8;
      const unsigned short* ga = embh + (size_t)(ibase + row) * D + kb + g;
      async_copy16(ga, &ldsA[r0 * 32]);
    }
#pragma unroll
    for (int pp = 0; pp < 2; ++pp) {
      // B: 128 rows -> 8 issues, two per wave
      int r0  = wave * 32 + pp * 16;  // wave-uniform
      int row = r0 + srow;
      int g   = (slot ^ ((row >> 1) & 3)) * 8;
      const unsigned short* gb = embh + (size_t)(jbase + row) * D + kb + g;
      async_copy16(gb, &ldsB[r0 * 32]);
    }
    __syncthreads();

    bf16x8 af[2], bfr[4];
#pragma unroll
    for (int x = 0; x < 2; ++x) af[x] = *(const bf16x8*)&ldsA[aoff[x]];
#pragma unroll
    for (int x = 0; x < 4; ++x) bfr[x] = *(const bf16x8*)&ldsB[boff[x]];
#pragma unroll
    for (int mi = 0; mi < 2; ++mi)
#pragma unroll
      for (int ni = 0; ni < 4; ++ni)
        acc[mi][ni] = __builtin_amdgcn_mfma_f32_16x16x32_bf16(
            af[mi], bfr[ni], acc[mi][ni], 0, 0, 0);
  }

  // ---- epilogue ----
  float sqj[4];
  int labj[4];
#pragma unroll
  for (int ni = 0; ni < 4; ++ni) {
    int jj = jbase + wn * 64 + ni * 16 + m15;
    sqj[ni] = sq[jj];
    labj[ni] = labels[jj];
  }

  ull colBp[4], colBn[4];
#pragma unroll
  for (int ni = 0; ni < 4; ++ni) { colBp[ni] = SENT_P; colBn[ni] = SENT_N; }

#pragma unroll
  for (int mi = 0; mi < 2; ++mi) {
#pragma unroll
    for (int r = 0; r < 4; ++r) {
      const int i = ibase + wm * 32 + mi * 16 + q * 4 + r;  // C/D row=(lane>>4)*4+r
      const float si = sq[i];
      const int li = labels[i];
      ull bp = SENT_P;
      ull bn = SENT_N;
#pragma unroll
      for (int ni = 0; ni < 4; ++ni) {
        int jj = jbase + wn * 64 + ni * 16 + m15;  // C/D col=lane&15
        if (jj > i) {                              // strict upper triangle only
          float dot = acc[mi][ni][r];
          float d2 = si + sqj[ni] - 2.0f * dot;
          float dist = sqrtf(fmaxf(d2, 0.0f));
          ull pv = ((ull)__float_as_uint(dist)) << 32;
          if (labj[ni] == li) {
            ull cr = pv | (unsigned)(~jj);  // max -> smallest idx wins ties
            bp = bp > cr ? bp : cr;
            ull cc = pv | (unsigned)(~i);
            colBp[ni] = colBp[ni] > cc ? colBp[ni] : cc;
          } else {
            ull cr = pv | (unsigned)jj;     // min -> smallest idx wins ties
            bn = bn < cr ? bn : cr;
            ull cc = pv | (unsigned)i;
            colBn[ni] = colBn[ni] < cc ? colBn[ni] : cc;
          }
        }
      }
      // row-i reduction across the 16 column lanes (m15 bits)
#pragma unroll
      for (int off = 1; off <= 8; off <<= 1) {
        ull op = __shfl_xor(bp, off, 64);
        ull on = __shfl_xor(bn, off, 64);
        bp = bp > op ? bp : op;
        bn = bn < on ? bn : on;
      }
      if (m15 == 0) {
        if (bp != SENT_P) atomicMax(&best_pos[i], bp);
        if (bn != SENT_N) atomicMin(&best_neg[i], bn);
      }
    }
  }

  // col-j reduction across the 4 q lane-groups
#pragma unroll
  for (int ni = 0; ni < 4; ++ni) {
    ull cp = colBp[ni], cn = colBn[ni];
#pragma unroll
    for (int off = 16; off <= 32; off <<= 1) {
      ull op = __shfl_xor(cp, off, 64);
      ull on = __shfl_xor(cn, off, 64);
      cp = cp > op ? cp : op;
      cn = cn < on ? cn : on;
    }
    if (q == 0) {
      int j = jbase + wn * 64 + ni * 16 + m15;
      if (cp != SENT_P) atomicMax(&best_pos[j], cp);
      if (cn != SENT_N) atomicMin(&best_neg[j], cn);
    }
  }
}

// ---------------- loss from packed bests (eps-corrected, no emb re-read) ----
__global__ void k_loss(const int* __restrict__ labels,
                       const ull* __restrict__ best_pos, const ull* __restrict__ best_neg,
                       const float* __restrict__ rs, const int* __restrict__ hist,
                       float* __restrict__ total, int* __restrict__ cnt) {
  const int i = blockIdx.x * blockDim.x + threadIdx.x;
  float per = 0.0f;
  int v = 0;
  int c = hist[labels[i]];
  if (c >= 2 && c < B) {  // has positive && has negative
    ull bp = best_pos[i], bn = best_neg[i];
    unsigned pRaw = ~(unsigned)bp;
    unsigned nRaw = (unsigned)bn;
    int p = pRaw < (unsigned)B ? (int)pRaw : 0;
    int n = nRaw < (unsigned)B ? (int)nRaw : 0;
    float distp = __uint_as_float((unsigned)(bp >> 32));
    float distn = __uint_as_float((unsigned)(bn >> 32));
    float ri = rs[i];
    // ||x + eps*1||^2 = ||x||^2 + 2 eps (sum_i - sum_j) + D eps^2
    const float e = 1e-6f, de2 = (float)D * 1e-12f;
    float dp2 = distp * distp + 2.0f * e * (ri - rs[p]) + de2;
    float dn2 = distn * distn + 2.0f * e * (ri - rs[n]) + de2;
    float dp = sqrtf(fmaxf(dp2, 0.0f));
    float dn = sqrtf(fmaxf(dn2, 0.0f));
    per = fmaxf(dp - dn + 0.3f, 0.0f);
    v = 1;
  }
  for (int off = 32; off; off >>= 1) {
    per += __shfl_down(per, off, 64);
    v   += __shfl_down(v, off, 64);
  }
  __shared__ float pps[4];
  __shared__ int pvs[4];
  int lane = threadIdx.x & 63, wave = threadIdx.x >> 6;
  if (lane == 0) { pps[wave] = per; pvs[wave] = v; }
  __syncthreads();
  if (threadIdx.x == 0) {
    atomicAdd(total, pps[0] + pps[1] + pps[2] + pps[3]);
    atomicAdd(cnt, pvs[0] + pvs[1] + pvs[2] + pvs[3]);
  }
}

// ---------------- finalize ---------------------------------------------------
__global__ void k_finalize(const float* total, const int* cnt, float* out) {
  int c = *cnt;
  out[0] = c > 0 ? (*total) / (float)c : 0.0f;
}

// ---------------- launch -----------------------------------------------------
extern "C" void kernel_launch(void* const* d_in, const int* in_sizes, int n_in,
                              void* d_out, int out_size, void* d_ws, size_t ws_size,
                              hipStream_t stream) {
  const float* emb = (const float*)d_in[0];
  const int* labels = (const int*)d_in[1];
  float* out = (float*)d_out;
  char* ws = (char*)d_ws;

  const size_t off_embh = 0;
  const size_t off_sq   = off_embh + (size_t)B * D * 2;   // 16 MiB
  const size_t off_rs   = off_sq + (size_t)B * 4;
  const size_t off_bp   = off_rs + (size_t)B * 4;
  const size_t off_bn   = off_bp + (size_t)B * 8;
  const size_t off_hist = off_bn + (size_t)B * 8;
  const size_t off_tot  = off_hist + NLAB * 4;
  const size_t off_cnt  = off_tot + 4;

  unsigned short* embh = (unsigned short*)(ws + off_embh);
  float* sq   = (float*)(ws + off_sq);
  float* rs   = (float*)(ws + off_rs);
  ull* bp     = (ull*)(ws + off_bp);
  ull* bn     = (ull*)(ws + off_bn);
  int* hist   = (int*)(ws + off_hist);
  float* tot  = (float*)(ws + off_tot);
  int* cnt    = (int*)(ws + off_cnt);

  hipLaunchKernelGGL(k_init, dim3(16), dim3(256), 0, stream, bp, bn, hist, tot, cnt);
  hipLaunchKernelGGL(k_convert_sq, dim3(B), dim3(256), 0, stream,
                     emb, labels, embh, sq, rs, hist);
  hipLaunchKernelGGL(k_gemm_select, dim3(1056), dim3(256), 0, stream,
                     embh, sq, labels, bp, bn);
  hipLaunchKernelGGL(k_loss, dim3(16), dim3(256), 0, stream,
                     labels, bp, bn, rs, hist, tot, cnt);
  hipLaunchKernelGGL(k_finalize, dim3(1), dim3(1), 0, stream, tot, cnt, out);
}

// Round 4
// 162.289 us; speedup vs baseline: 1.8199x; 1.0473x over previous
//
#include <hip/hip_runtime.h>
#include <stdint.h>

#define B 4096
#define D 2048
#define NLAB 128
#define BK 64  // k-slab per barrier (elements)

typedef unsigned long long ull;
typedef __bf16 bf16x8 __attribute__((ext_vector_type(8)));
typedef float f32x4 __attribute__((ext_vector_type(4)));

#define SENT_P 0x00000000FFFFFFFFull  // dist=0.0, ~idx -> decodes to idx 0
#define SENT_N (~0ull)                // +inf

// ---------------- async global->LDS (16B per lane, wave-uniform LDS base) ----
__device__ __forceinline__ void async_copy16(const unsigned short* g, unsigned short* l) {
  __builtin_amdgcn_global_load_lds(
      (const __attribute__((address_space(1))) unsigned int*)g,
      (__attribute__((address_space(3))) unsigned int*)l,
      16, 0, 0);
}

// ---------------- init ------------------------------------------------------
__global__ void k_init(ull* bp, ull* bn, int* hist, float* total, int* cnt) {
  int i = blockIdx.x * blockDim.x + threadIdx.x;
  if (i < B) {
    bp[i] = SENT_P;
    bn[i] = SENT_N;
  }
  if (i < NLAB) hist[i] = 0;
  if (i == 0) { *total = 0.0f; *cnt = 0; }
}

// ---------------- fp32 -> bf16 (RNE) + row sq-norm + row sum + hist ---------
__device__ __forceinline__ unsigned f2bf_pack(float lo, float hi) {
  unsigned a = __float_as_uint(lo), b = __float_as_uint(hi);
  a = (a + 0x7FFFu + ((a >> 16) & 1u)) >> 16;
  b = (b + 0x7FFFu + ((b >> 16) & 1u)) >> 16;
  return a | (b << 16);
}

__global__ void k_convert_sq(const float* __restrict__ emb,
                             const int* __restrict__ labels,
                             unsigned short* __restrict__ embh,
                             float* __restrict__ sq,
                             float* __restrict__ rs,
                             int* __restrict__ hist) {
  const int row = blockIdx.x, t = threadIdx.x;
  const float4* src = (const float4*)(emb + (size_t)row * D);
  float4 v0 = src[2 * t], v1 = src[2 * t + 1];
  float s = v0.x * v0.x + v0.y * v0.y + v0.z * v0.z + v0.w * v0.w
          + v1.x * v1.x + v1.y * v1.y + v1.z * v1.z + v1.w * v1.w;
  float sm = v0.x + v0.y + v0.z + v0.w + v1.x + v1.y + v1.z + v1.w;
  uint4 o;
  o.x = f2bf_pack(v0.x, v0.y);
  o.y = f2bf_pack(v0.z, v0.w);
  o.z = f2bf_pack(v1.x, v1.y);
  o.w = f2bf_pack(v1.z, v1.w);
  ((uint4*)(embh + (size_t)row * D))[t] = o;

  for (int off = 32; off; off >>= 1) {
    s  += __shfl_down(s, off, 64);
    sm += __shfl_down(sm, off, 64);
  }
  __shared__ float ps[4], pm[4];
  int lane = t & 63, wave = t >> 6;
  if (lane == 0) { ps[wave] = s; pm[wave] = sm; }
  __syncthreads();
  if (t == 0) {
    sq[row] = ps[0] + ps[1] + ps[2] + ps[3];
    rs[row] = pm[0] + pm[1] + pm[2] + pm[3];
    atomicAdd(&hist[labels[row]], 1);
  }
}

// ---------------- fused symmetric GEMM + hard pos/neg selection -------------
// 64x128 tiles covering the strict upper triangle (j > i): 1056 blocks.
// BK=64 (32 k-iterations, 16 MFMA/wave per barrier pair). 4 waves (2x2),
// each wave 32x64 via 2x4 mfma_f32_16x16x32_bf16 over 2 k-slabs.
// Rows are 128B = 8 chunks of 16B; chunk placed at slot = chunk ^ (row&7)
// so fragment ds_read_b128 spreads each q-group over 8 slots (2-way = free)
// while global_load_lds keeps its wave-uniform-base contiguous layout.
__launch_bounds__(256, 4)
__global__ void k_gemm_select(const unsigned short* __restrict__ embh,
                              const float* __restrict__ sq,
                              const int* __restrict__ labels,
                              ull* __restrict__ best_pos,
                              ull* __restrict__ best_neg) {
  __shared__ unsigned short ldsA[64 * BK];    // 8 KB
  __shared__ unsigned short ldsB[128 * BK];   // 16 KB

  // linear bid -> (by in [0,64), bx in [0,32)) with bx*128+127 > by*64
  int rem = blockIdx.x, p = 0;
  while (rem >= 2 * (32 - p)) { rem -= 2 * (32 - p); ++p; }
  int by = 2 * p;
  int c = 32 - p;
  if (rem >= c) { by += 1; rem -= c; }
  const int bx = p + rem;

  const int tid  = threadIdx.x;
  const int lane = tid & 63;
  const int wave = tid >> 6;
  const int wm = wave >> 1, wn = wave & 1;
  const int q = lane >> 4, m15 = lane & 15;
  const int ibase = by * 64, jbase = bx * 128;

  // fragment read offsets (elements) for slab s, frag row-group x:
  //   row = base + x*16 + m15 ; chunk = s*4 + q ; slot = chunk ^ (row & 7)
  int aoff[2][2], boff[2][4];
#pragma unroll
  for (int s = 0; s < 2; ++s) {
#pragma unroll
    for (int x = 0; x < 2; ++x) {
      int row = wm * 32 + x * 16 + m15;
      aoff[s][x] = row * BK + ((s * 4 + q) ^ (row & 7)) * 8;
    }
#pragma unroll
    for (int x = 0; x < 4; ++x) {
      int row = wn * 64 + x * 16 + m15;
      boff[s][x] = row * BK + ((s * 4 + q) ^ (row & 7)) * 8;
    }
  }

  const int srow = lane >> 3;  // row within 8-row staging group
  const int slot = lane & 7;   // 16B slot within 128B row

  f32x4 acc[2][4];
  const f32x4 z = {0.f, 0.f, 0.f, 0.f};
#pragma unroll
  for (int a = 0; a < 2; ++a)
#pragma unroll
    for (int b = 0; b < 4; ++b) acc[a][b] = z;

  for (int kb = 0; kb < D; kb += BK) {
    __syncthreads();
#pragma unroll
    for (int pp = 0; pp < 2; ++pp) {
      // A: 64 rows -> 8 issues (8 rows each), two per wave
      int r0  = wave * 16 + pp * 8;  // wave-uniform
      int row = r0 + srow;
      int g   = (slot ^ (row & 7)) * 8;
      const unsigned short* ga = embh + (size_t)(ibase + row) * D + kb + g;
      async_copy16(ga, &ldsA[r0 * BK]);
    }
#pragma unroll
    for (int pp = 0; pp < 4; ++pp) {
      // B: 128 rows -> 16 issues, four per wave
      int r0  = wave * 32 + pp * 8;  // wave-uniform
      int row = r0 + srow;
      int g   = (slot ^ (row & 7)) * 8;
      const unsigned short* gb = embh + (size_t)(jbase + row) * D + kb + g;
      async_copy16(gb, &ldsB[r0 * BK]);
    }
    __syncthreads();

    bf16x8 af[2][2], bfr[2][4];
#pragma unroll
    for (int s = 0; s < 2; ++s) {
#pragma unroll
      for (int x = 0; x < 2; ++x) af[s][x] = *(const bf16x8*)&ldsA[aoff[s][x]];
#pragma unroll
      for (int x = 0; x < 4; ++x) bfr[s][x] = *(const bf16x8*)&ldsB[boff[s][x]];
    }
#pragma unroll
    for (int s = 0; s < 2; ++s)
#pragma unroll
      for (int mi = 0; mi < 2; ++mi)
#pragma unroll
        for (int ni = 0; ni < 4; ++ni)
          acc[mi][ni] = __builtin_amdgcn_mfma_f32_16x16x32_bf16(
              af[s][mi], bfr[s][ni], acc[mi][ni], 0, 0, 0);
  }

  // ---- epilogue ----
  float sqj[4];
  int labj[4];
#pragma unroll
  for (int ni = 0; ni < 4; ++ni) {
    int jj = jbase + wn * 64 + ni * 16 + m15;
    sqj[ni] = sq[jj];
    labj[ni] = labels[jj];
  }

  ull colBp[4], colBn[4];
#pragma unroll
  for (int ni = 0; ni < 4; ++ni) { colBp[ni] = SENT_P; colBn[ni] = SENT_N; }

#pragma unroll
  for (int mi = 0; mi < 2; ++mi) {
#pragma unroll
    for (int r = 0; r < 4; ++r) {
      const int i = ibase + wm * 32 + mi * 16 + q * 4 + r;  // C/D row=(lane>>4)*4+r
      const float si = sq[i];
      const int li = labels[i];
      ull bp = SENT_P;
      ull bn = SENT_N;
#pragma unroll
      for (int ni = 0; ni < 4; ++ni) {
        int jj = jbase + wn * 64 + ni * 16 + m15;  // C/D col=lane&15
        if (jj > i) {                              // strict upper triangle only
          float dot = acc[mi][ni][r];
          float d2 = si + sqj[ni] - 2.0f * dot;
          float dist = sqrtf(fmaxf(d2, 0.0f));
          ull pv = ((ull)__float_as_uint(dist)) << 32;
          if (labj[ni] == li) {
            ull cr = pv | (unsigned)(~jj);  // max -> smallest idx wins ties
            bp = bp > cr ? bp : cr;
            ull cc = pv | (unsigned)(~i);
            colBp[ni] = colBp[ni] > cc ? colBp[ni] : cc;
          } else {
            ull cr = pv | (unsigned)jj;     // min -> smallest idx wins ties
            bn = bn < cr ? bn : cr;
            ull cc = pv | (unsigned)i;
            colBn[ni] = colBn[ni] < cc ? colBn[ni] : cc;
          }
        }
      }
      // row-i reduction across the 16 column lanes (m15 bits)
#pragma unroll
      for (int off = 1; off <= 8; off <<= 1) {
        ull op = __shfl_xor(bp, off, 64);
        ull on = __shfl_xor(bn, off, 64);
        bp = bp > op ? bp : op;
        bn = bn < on ? bn : on;
      }
      if (m15 == 0) {
        if (bp != SENT_P) atomicMax(&best_pos[i], bp);
        if (bn != SENT_N) atomicMin(&best_neg[i], bn);
      }
    }
  }

  // col-j reduction across the 4 q lane-groups
#pragma unroll
  for (int ni = 0; ni < 4; ++ni) {
    ull cp = colBp[ni], cn = colBn[ni];
#pragma unroll
    for (int off = 16; off <= 32; off <<= 1) {
      ull op = __shfl_xor(cp, off, 64);
      ull on = __shfl_xor(cn, off, 64);
      cp = cp > op ? cp : op;
      cn = cn < on ? cn : on;
    }
    if (q == 0) {
      int j = jbase + wn * 64 + ni * 16 + m15;
      if (cp != SENT_P) atomicMax(&best_pos[j], cp);
      if (cn != SENT_N) atomicMin(&best_neg[j], cn);
    }
  }
}

// ---------------- loss from packed bests (eps-corrected, no emb re-read) ----
__global__ void k_loss(const int* __restrict__ labels,
                       const ull* __restrict__ best_pos, const ull* __restrict__ best_neg,
                       const float* __restrict__ rs, const int* __restrict__ hist,
                       float* __restrict__ total, int* __restrict__ cnt) {
  const int i = blockIdx.x * blockDim.x + threadIdx.x;
  float per = 0.0f;
  int v = 0;
  int c = hist[labels[i]];
  if (c >= 2 && c < B) {  // has positive && has negative
    ull bp = best_pos[i], bn = best_neg[i];
    unsigned pRaw = ~(unsigned)bp;
    unsigned nRaw = (unsigned)bn;
    int p = pRaw < (unsigned)B ? (int)pRaw : 0;
    int n = nRaw < (unsigned)B ? (int)nRaw : 0;
    float distp = __uint_as_float((unsigned)(bp >> 32));
    float distn = __uint_as_float((unsigned)(bn >> 32));
    float ri = rs[i];
    // ||x + eps*1||^2 = ||x||^2 + 2 eps (sum_i - sum_j) + D eps^2
    const float e = 1e-6f, de2 = (float)D * 1e-12f;
    float dp2 = distp * distp + 2.0f * e * (ri - rs[p]) + de2;
    float dn2 = distn * distn + 2.0f * e * (ri - rs[n]) + de2;
    float dp = sqrtf(fmaxf(dp2, 0.0f));
    float dn = sqrtf(fmaxf(dn2, 0.0f));
    per = fmaxf(dp - dn + 0.3f, 0.0f);
    v = 1;
  }
  for (int off = 32; off; off >>= 1) {
    per += __shfl_down(per, off, 64);
    v   += __shfl_down(v, off, 64);
  }
  __shared__ float pps[4];
  __shared__ int pvs[4];
  int lane = threadIdx.x & 63, wave = threadIdx.x >> 6;
  if (lane == 0) { pps[wave] = per; pvs[wave] = v; }
  __syncthreads();
  if (threadIdx.x == 0) {
    atomicAdd(total, pps[0] + pps[1] + pps[2] + pps[3]);
    atomicAdd(cnt, pvs[0] + pvs[1] + pvs[2] + pvs[3]);
  }
}

// ---------------- finalize ---------------------------------------------------
__global__ void k_finalize(const float* total, const int* cnt, float* out) {
  int c = *cnt;
  out[0] = c > 0 ? (*total) / (float)c : 0.0f;
}

// ---------------- launch -----------------------------------------------------
extern "C" void kernel_launch(void* const* d_in, const int* in_sizes, int n_in,
                              void* d_out, int out_size, void* d_ws, size_t ws_size,
                              hipStream_t stream) {
  const float* emb = (const float*)d_in[0];
  const int* labels = (const int*)d_in[1];
  float* out = (float*)d_out;
  char* ws = (char*)d_ws;

  const size_t off_embh = 0;
  const size_t off_sq   = off_embh + (size_t)B * D * 2;   // 16 MiB
  const size_t off_rs   = off_sq + (size_t)B * 4;
  const size_t off_bp   = off_rs + (size_t)B * 4;
  const size_t off_bn   = off_bp + (size_t)B * 8;
  const size_t off_hist = off_bn + (size_t)B * 8;
  const size_t off_tot  = off_hist + NLAB * 4;
  const size_t off_cnt  = off_tot + 4;

  unsigned short* embh = (unsigned short*)(ws + off_embh);
  float* sq   = (float*)(ws + off_sq);
  float* rs   = (float*)(ws + off_rs);
  ull* bp     = (ull*)(ws + off_bp);
  ull* bn     = (ull*)(ws + off_bn);
  int* hist   = (int*)(ws + off_hist);
  float* tot  = (float*)(ws + off_tot);
  int* cnt    = (int*)(ws + off_cnt);

  hipLaunchKernelGGL(k_init, dim3(16), dim3(256), 0, stream, bp, bn, hist, tot, cnt);
  hipLaunchKernelGGL(k_convert_sq, dim3(B), dim3(256), 0, stream,
                     emb, labels, embh, sq, rs, hist);
  hipLaunchKernelGGL(k_gemm_select, dim3(1056), dim3(256), 0, stream,
                     embh, sq, labels, bp, bn);
  hipLaunchKernelGGL(k_loss, dim3(16), dim3(256), 0, stream,
                     labels, bp, bn, rs, hist, tot, cnt);
  hipLaunchKernelGGL(k_finalize, dim3(1), dim3(1), 0, stream, tot, cnt, out);
}

// Round 5
// 152.581 us; speedup vs baseline: 1.9357x; 1.0636x over previous
//
#include <hip/hip_runtime.h>
#include <stdint.h>

#define B 4096
#define D 2048
#define BK 64           // k-slab per pipeline stage (elements)
#define NITER (D / BK)  // 32

typedef unsigned long long ull;
typedef __bf16 bf16x8 __attribute__((ext_vector_type(8)));
typedef float f32x4 __attribute__((ext_vector_type(4)));

#define SENT_P 0x00000000FFFFFFFFull  // dist=0.0, ~idx -> "no positive seen"
#define SENT_N (~0ull)                // +inf      -> "no negative seen"

// ---------------- async global->LDS (16B per lane, wave-uniform LDS base) ----
__device__ __forceinline__ void async_copy16(const unsigned short* g, unsigned short* l) {
  __builtin_amdgcn_global_load_lds(
      (const __attribute__((address_space(1))) unsigned int*)g,
      (__attribute__((address_space(3))) unsigned int*)l,
      16, 0, 0);
}

// ---------------- fp32 -> bf16 (RNE) + row sq-norm/sum + sentinel init ------
__device__ __forceinline__ unsigned f2bf_pack(float lo, float hi) {
  unsigned a = __float_as_uint(lo), b = __float_as_uint(hi);
  a = (a + 0x7FFFu + ((a >> 16) & 1u)) >> 16;
  b = (b + 0x7FFFu + ((b >> 16) & 1u)) >> 16;
  return a | (b << 16);
}

__global__ void k_convert_sq(const float* __restrict__ emb,
                             unsigned short* __restrict__ embh,
                             float* __restrict__ sq,
                             float* __restrict__ rs,
                             ull* __restrict__ bp,
                             ull* __restrict__ bn) {
  const int row = blockIdx.x, t = threadIdx.x;
  const float4* src = (const float4*)(emb + (size_t)row * D);
  float4 v0 = src[2 * t], v1 = src[2 * t + 1];
  float s = v0.x * v0.x + v0.y * v0.y + v0.z * v0.z + v0.w * v0.w
          + v1.x * v1.x + v1.y * v1.y + v1.z * v1.z + v1.w * v1.w;
  float sm = v0.x + v0.y + v0.z + v0.w + v1.x + v1.y + v1.z + v1.w;
  uint4 o;
  o.x = f2bf_pack(v0.x, v0.y);
  o.y = f2bf_pack(v0.z, v0.w);
  o.z = f2bf_pack(v1.x, v1.y);
  o.w = f2bf_pack(v1.z, v1.w);
  ((uint4*)(embh + (size_t)row * D))[t] = o;

  for (int off = 32; off; off >>= 1) {
    s  += __shfl_down(s, off, 64);
    sm += __shfl_down(sm, off, 64);
  }
  __shared__ float ps[4], pm[4];
  int lane = t & 63, wave = t >> 6;
  if (lane == 0) { ps[wave] = s; pm[wave] = sm; }
  __syncthreads();
  if (t == 0) {
    sq[row] = ps[0] + ps[1] + ps[2] + ps[3];
    rs[row] = pm[0] + pm[1] + pm[2] + pm[3];
    bp[row] = SENT_P;
    bn[row] = SENT_N;
  }
}

// ---------------- fused symmetric GEMM + hard pos/neg selection -------------
// 64x128 tiles covering the strict upper triangle (j > i): 1056 blocks.
// Single-barrier software-pipelined K-loop: double-buffered LDS, prefetch
// slab k+1 via global_load_lds right after the barrier, compute slab k.
// At the `s_waitcnt vmcnt(0); s_barrier` point the only outstanding vmem
// ops are the current slab's, so nothing extra is drained and the prefetch
// overlaps the whole MFMA phase.
// Rows are 128B = 8 chunks of 16B; chunk placed at slot = chunk ^ (row&7)
// keeps fragment ds_read_b128 2-way (free) while global_load_lds keeps its
// wave-uniform-base contiguous layout.
__launch_bounds__(256, 3)
__global__ void k_gemm_select(const unsigned short* __restrict__ embh,
                              const float* __restrict__ sq,
                              const int* __restrict__ labels,
                              ull* __restrict__ best_pos,
                              ull* __restrict__ best_neg) {
  __shared__ unsigned short ldsA[2][64 * BK];    // 2 x 8 KB
  __shared__ unsigned short ldsB[2][128 * BK];   // 2 x 16 KB

  // linear bid -> (by in [0,64), bx in [0,32)) with bx*128+127 > by*64
  int rem = blockIdx.x, p = 0;
  while (rem >= 2 * (32 - p)) { rem -= 2 * (32 - p); ++p; }
  int by = 2 * p;
  int c = 32 - p;
  if (rem >= c) { by += 1; rem -= c; }
  const int bx = p + rem;

  const int tid  = threadIdx.x;
  const int lane = tid & 63;
  const int wave = tid >> 6;
  const int wm = wave >> 1, wn = wave & 1;
  const int q = lane >> 4, m15 = lane & 15;
  const int ibase = by * 64, jbase = bx * 128;

  // fragment read offsets (elements) for slab s, frag row-group x:
  //   row = base + x*16 + m15 ; chunk = s*4 + q ; slot = chunk ^ (row & 7)
  int aoff[2][2], boff[2][4];
#pragma unroll
  for (int s = 0; s < 2; ++s) {
#pragma unroll
    for (int x = 0; x < 2; ++x) {
      int row = wm * 32 + x * 16 + m15;
      aoff[s][x] = row * BK + ((s * 4 + q) ^ (row & 7)) * 8;
    }
#pragma unroll
    for (int x = 0; x < 4; ++x) {
      int row = wn * 64 + x * 16 + m15;
      boff[s][x] = row * BK + ((s * 4 + q) ^ (row & 7)) * 8;
    }
  }

  // staging addresses: 6 global_load_lds issues per wave per slab
  const int srow = lane >> 3;  // row within 8-row staging group
  const int slot = lane & 7;   // 16B slot within 128B row
  const unsigned short* gA[2];
  const unsigned short* gB[4];
  int lA[2], lB[4];
#pragma unroll
  for (int pp = 0; pp < 2; ++pp) {
    int r0  = wave * 16 + pp * 8;  // wave-uniform
    int row = r0 + srow;
    int g   = (slot ^ (row & 7)) * 8;
    gA[pp] = embh + (size_t)(ibase + row) * D + g;
    lA[pp] = r0 * BK;
  }
#pragma unroll
  for (int pp = 0; pp < 4; ++pp) {
    int r0  = wave * 32 + pp * 8;  // wave-uniform
    int row = r0 + srow;
    int g   = (slot ^ (row & 7)) * 8;
    gB[pp] = embh + (size_t)(jbase + row) * D + g;
    lB[pp] = r0 * BK;
  }

  f32x4 acc[2][4];
  const f32x4 z = {0.f, 0.f, 0.f, 0.f};
#pragma unroll
  for (int a = 0; a < 2; ++a)
#pragma unroll
    for (int b = 0; b < 4; ++b) acc[a][b] = z;

  // prologue: stage slab 0 into buffer 0
#pragma unroll
  for (int pp = 0; pp < 2; ++pp) async_copy16(gA[pp], &ldsA[0][lA[pp]]);
#pragma unroll
  for (int pp = 0; pp < 4; ++pp) async_copy16(gB[pp], &ldsB[0][lB[pp]]);

  for (int it = 0; it < NITER; ++it) {
    // only the current slab's 6 loads are outstanding here -> nothing
    // extra is drained; barrier also orders last iter's LDS reads (already
    // consumed by their MFMAs) before the prefetch overwrite below.
    asm volatile("s_waitcnt vmcnt(0)\n\ts_barrier" ::: "memory");
    const int sel = it & 1;
    if (it + 1 < NITER) {
      const int nsel = sel ^ 1;
      const int ko = (it + 1) * BK;
#pragma unroll
      for (int pp = 0; pp < 2; ++pp) async_copy16(gA[pp] + ko, &ldsA[nsel][lA[pp]]);
#pragma unroll
      for (int pp = 0; pp < 4; ++pp) async_copy16(gB[pp] + ko, &ldsB[nsel][lB[pp]]);
    }

    bf16x8 af[2][2], bfr[2][4];
#pragma unroll
    for (int s = 0; s < 2; ++s) {
#pragma unroll
      for (int x = 0; x < 2; ++x) af[s][x] = *(const bf16x8*)&ldsA[sel][aoff[s][x]];
#pragma unroll
      for (int x = 0; x < 4; ++x) bfr[s][x] = *(const bf16x8*)&ldsB[sel][boff[s][x]];
    }
#pragma unroll
    for (int s = 0; s < 2; ++s)
#pragma unroll
      for (int mi = 0; mi < 2; ++mi)
#pragma unroll
        for (int ni = 0; ni < 4; ++ni)
          acc[mi][ni] = __builtin_amdgcn_mfma_f32_16x16x32_bf16(
              af[s][mi], bfr[s][ni], acc[mi][ni], 0, 0, 0);
  }

  // ---- epilogue ----
  float sqj[4];
  int labj[4];
#pragma unroll
  for (int ni = 0; ni < 4; ++ni) {
    int jj = jbase + wn * 64 + ni * 16 + m15;
    sqj[ni] = sq[jj];
    labj[ni] = labels[jj];
  }

  ull colBp[4], colBn[4];
#pragma unroll
  for (int ni = 0; ni < 4; ++ni) { colBp[ni] = SENT_P; colBn[ni] = SENT_N; }

#pragma unroll
  for (int mi = 0; mi < 2; ++mi) {
#pragma unroll
    for (int r = 0; r < 4; ++r) {
      const int i = ibase + wm * 32 + mi * 16 + q * 4 + r;  // C/D row=(lane>>4)*4+r
      const float si = sq[i];
      const int li = labels[i];
      ull bp = SENT_P;
      ull bn = SENT_N;
#pragma unroll
      for (int ni = 0; ni < 4; ++ni) {
        int jj = jbase + wn * 64 + ni * 16 + m15;  // C/D col=lane&15
        if (jj > i) {                              // strict upper triangle only
          float dot = acc[mi][ni][r];
          float d2 = si + sqj[ni] - 2.0f * dot;
          float dist = sqrtf(fmaxf(d2, 0.0f));
          ull pv = ((ull)__float_as_uint(dist)) << 32;
          if (labj[ni] == li) {
            ull cr = pv | (unsigned)(~jj);  // max -> smallest idx wins ties
            bp = bp > cr ? bp : cr;
            ull cc = pv | (unsigned)(~i);
            colBp[ni] = colBp[ni] > cc ? colBp[ni] : cc;
          } else {
            ull cr = pv | (unsigned)jj;     // min -> smallest idx wins ties
            bn = bn < cr ? bn : cr;
            ull cc = pv | (unsigned)i;
            colBn[ni] = colBn[ni] < cc ? colBn[ni] : cc;
          }
        }
      }
      // row-i reduction across the 16 column lanes (m15 bits)
#pragma unroll
      for (int off = 1; off <= 8; off <<= 1) {
        ull op = __shfl_xor(bp, off, 64);
        ull on = __shfl_xor(bn, off, 64);
        bp = bp > op ? bp : op;
        bn = bn < on ? bn : on;
      }
      if (m15 == 0) {
        if (bp != SENT_P) atomicMax(&best_pos[i], bp);
        if (bn != SENT_N) atomicMin(&best_neg[i], bn);
      }
    }
  }

  // col-j reduction across the 4 q lane-groups
#pragma unroll
  for (int ni = 0; ni < 4; ++ni) {
    ull cp = colBp[ni], cn = colBn[ni];
#pragma unroll
    for (int off = 16; off <= 32; off <<= 1) {
      ull op = __shfl_xor(cp, off, 64);
      ull on = __shfl_xor(cn, off, 64);
      cp = cp > op ? cp : op;
      cn = cn < on ? cn : on;
    }
    if (q == 0) {
      int j = jbase + wn * 64 + ni * 16 + m15;
      if (cp != SENT_P) atomicMax(&best_pos[j], cp);
      if (cn != SENT_N) atomicMin(&best_neg[j], cn);
    }
  }
}

// ---------------- loss + finalize in one single-block kernel ----------------
// valid anchor <=> bp != SENT_P (some positive seen) && bn != SENT_N.
// dp/dn from packed fp32 dist, eps-corrected:
//   ||x + eps*1||^2 = ||x||^2 + 2 eps (sum_i - sum_j) + D eps^2
__global__ void k_loss_final(const int* __restrict__ labels,
                             const ull* __restrict__ best_pos,
                             const ull* __restrict__ best_neg,
                             const float* __restrict__ rs,
                             float* __restrict__ out) {
  float per = 0.0f;
  int v = 0;
  for (int i = threadIdx.x; i < B; i += 1024) {
    ull bp = best_pos[i], bn = best_neg[i];
    if (bp != SENT_P && bn != SENT_N) {
      unsigned pRaw = ~(unsigned)bp;
      unsigned nRaw = (unsigned)bn;
      int pi = pRaw < (unsigned)B ? (int)pRaw : 0;
      int ni = nRaw < (unsigned)B ? (int)nRaw : 0;
      float distp = __uint_as_float((unsigned)(bp >> 32));
      float distn = __uint_as_float((unsigned)(bn >> 32));
      float ri = rs[i];
      const float e = 1e-6f, de2 = (float)D * 1e-12f;
      float dp2 = distp * distp + 2.0f * e * (ri - rs[pi]) + de2;
      float dn2 = distn * distn + 2.0f * e * (ri - rs[ni]) + de2;
      float dp = sqrtf(fmaxf(dp2, 0.0f));
      float dn = sqrtf(fmaxf(dn2, 0.0f));
      per += fmaxf(dp - dn + 0.3f, 0.0f);
      v += 1;
    }
  }
  for (int off = 32; off; off >>= 1) {
    per += __shfl_down(per, off, 64);
    v   += __shfl_down(v, off, 64);
  }
  __shared__ float pps[16];
  __shared__ int pvs[16];
  int lane = threadIdx.x & 63, wave = threadIdx.x >> 6;
  if (lane == 0) { pps[wave] = per; pvs[wave] = v; }
  __syncthreads();
  if (threadIdx.x == 0) {
    float t = 0.f;
    int cv = 0;
#pragma unroll
    for (int w = 0; w < 16; ++w) { t += pps[w]; cv += pvs[w]; }
    out[0] = cv > 0 ? t / (float)cv : 0.0f;
  }
}

// ---------------- launch -----------------------------------------------------
extern "C" void kernel_launch(void* const* d_in, const int* in_sizes, int n_in,
                              void* d_out, int out_size, void* d_ws, size_t ws_size,
                              hipStream_t stream) {
  const float* emb = (const float*)d_in[0];
  const int* labels = (const int*)d_in[1];
  float* out = (float*)d_out;
  char* ws = (char*)d_ws;

  const size_t off_embh = 0;
  const size_t off_sq   = off_embh + (size_t)B * D * 2;   // 16 MiB
  const size_t off_rs   = off_sq + (size_t)B * 4;
  const size_t off_bp   = off_rs + (size_t)B * 4;
  const size_t off_bn   = off_bp + (size_t)B * 8;

  unsigned short* embh = (unsigned short*)(ws + off_embh);
  float* sq   = (float*)(ws + off_sq);
  float* rs   = (float*)(ws + off_rs);
  ull* bp     = (ull*)(ws + off_bp);
  ull* bn     = (ull*)(ws + off_bn);

  hipLaunchKernelGGL(k_convert_sq, dim3(B), dim3(256), 0, stream,
                     emb, embh, sq, rs, bp, bn);
  hipLaunchKernelGGL(k_gemm_select, dim3(1056), dim3(256), 0, stream,
                     embh, sq, labels, bp, bn);
  hipLaunchKernelGGL(k_loss_final, dim3(1), dim3(1024), 0, stream,
                     labels, bp, bn, rs, out);
}